// Round 5
// baseline (403.457 us; speedup 1.0000x reference)
//
#include <hip/hip_runtime.h>
#include <math.h>

#define B_ 16
#define L_ 512
#define D_ 768
#define H_ 12
#define K_ 128
#define U_ 256
#define NH_ 4
#define HD_ 64
#define OUTROWS_ 130   // 1 class + 128 preserved + 1 new
#define IMP_G_ 96      // importance partial groups: 48 chunks x 2 row-halves

// ---------------------------------------------------------------------------
// Block reduction helpers (256-thread = 4 waves).
// ---------------------------------------------------------------------------
__device__ __forceinline__ float blk_max256(float v, float* red, int t) {
  __syncthreads();
  #pragma unroll
  for (int o = 32; o > 0; o >>= 1) v = fmaxf(v, __shfl_down(v, o, 64));
  if ((t & 63) == 0) red[t >> 6] = v;
  __syncthreads();
  if (t == 0) {
    float r = fmaxf(fmaxf(red[0], red[1]), fmaxf(red[2], red[3]));
    red[0] = r;
  }
  __syncthreads();
  return red[0];
}

__device__ __forceinline__ float blk_sum256(float v, float* red, int t) {
  __syncthreads();
  #pragma unroll
  for (int o = 32; o > 0; o >>= 1) v += __shfl_down(v, o, 64);
  if ((t & 63) == 0) red[t >> 6] = v;
  __syncthreads();
  if (t == 0) red[0] = red[0] + red[1] + red[2] + red[3];
  __syncthreads();
  return red[0];
}

// ---------------------------------------------------------------------------
// Fused dispatch A: grid (64, B), 256 threads.
//   blockIdx.x <  48: importance partials (201 MB stream, the HBM floor)
//   blockIdx.x >= 48: sentence partials (25 MB stream, overlaps under it)
// ---------------------------------------------------------------------------
__global__ __launch_bounds__(256) void imp_sent_kernel(
    const float* __restrict__ scores, const float* __restrict__ hidden,
    const float* __restrict__ mask, float* __restrict__ part,
    float* __restrict__ sent_part) {
  const int b = blockIdx.y, t = threadIdx.x;
  if (blockIdx.x < 48) {
    const int chunk = blockIdx.x;
    const int qcol = t & 127;
    const int rhalf = t >> 7;
    const float4* base = (const float4*)scores +
        ((size_t)(b * (H_ * L_) + chunk * 128 + rhalf)) * 128 + qcol;
    float4 a = make_float4(0.f, 0.f, 0.f, 0.f);
    #pragma unroll 8
    for (int r = 0; r < 64; ++r) {
      float4 v = base[(size_t)r * 256];
      a.x += v.x; a.y += v.y; a.z += v.z; a.w += v.w;
    }
    const float s = 1.0f / 12.0f;
    float4 o = make_float4(a.x * s, a.y * s, a.z * s, a.w * s);
    ((float4*)part)[((size_t)b * IMP_G_ + chunk * 2 + rhalf) * 128 + qcol] = o;
  } else {
    __shared__ float att[L_];
    __shared__ float red[4];
    const int chunk = blockIdx.x - 48;
    const float m0 = mask[b * L_ + t];
    const float m1 = mask[b * L_ + 256 + t];
    float mx = blk_max256(fmaxf(m0, m1), red, t);
    const float e0 = expf(m0 - mx);
    const float e1 = expf(m1 - mx);
    float se = blk_sum256(e0 + e1, red, t);
    att[t] = e0 / se;
    att[t + 256] = e1 / se;
    __syncthreads();
    const int l0 = chunk * 32;
    const float* hp = hidden + ((size_t)b * L_ + l0) * D_;
    float a0 = 0.f, a1 = 0.f, a2 = 0.f;
    #pragma unroll 8
    for (int l = 0; l < 32; ++l) {
      const float av = att[l0 + l];
      const float* hr = hp + (size_t)l * D_;
      a0 += av * hr[t];
      a1 += av * hr[t + 256];
      a2 += av * hr[t + 512];
    }
    float* sp = sent_part + ((size_t)b * 16 + chunk) * D_;
    sp[t] = a0; sp[t + 256] = a1; sp[t + 512] = a2;
  }
}

// ---------------------------------------------------------------------------
// Fused dispatch B: blocks 0..63 = qproj per (b,h); blocks 64..79 = topk+gather.
// ---------------------------------------------------------------------------
__global__ __launch_bounds__(768) void qproj_topk_kernel(
    const float* __restrict__ sent_part, const float* __restrict__ Wq,
    const float* __restrict__ Wk, float* __restrict__ wqe,
    const float* __restrict__ part, const float* __restrict__ mask,
    const float* __restrict__ hidden, float* __restrict__ out0,
    float* __restrict__ out1) {
  __shared__ float s[D_];
  __shared__ float qvh[HD_];
  __shared__ float v[L_];
  __shared__ int lidx[K_];
  __shared__ int wcnt[12];
  const int t = threadIdx.x;
  const int wave = t >> 6, lane = t & 63;

  if (blockIdx.x < 64) {
    const int b = blockIdx.x >> 2, h = blockIdx.x & 3;
    {
      const float* sp = sent_part + (size_t)b * 16 * D_ + t;
      float a = 0.f;
      #pragma unroll
      for (int c = 0; c < 16; ++c) a += sp[(size_t)c * D_];
      s[t] = a;
    }
    __syncthreads();
    for (int u = wave; u < HD_; u += 12) {
      const float* wr = Wq + (size_t)(h * HD_ + u) * D_;
      float acc = 0.f;
      #pragma unroll
      for (int k = 0; k < 12; ++k) {
        const int d = lane + (k << 6);
        acc += wr[d] * s[d];
      }
      #pragma unroll
      for (int o = 32; o > 0; o >>= 1) acc += __shfl_down(acc, o, 64);
      if (lane == 0) qvh[u] = acc;
    }
    __syncthreads();
    {
      float acc = 0.f;
      const float* wk = Wk + (size_t)(h * HD_) * D_ + t;
      #pragma unroll 4
      for (int j = 0; j < HD_; ++j) acc += qvh[j] * wk[(size_t)j * D_];
      wqe[((size_t)b * NH_ + h) * D_ + t] = acc;
    }
  } else {
    const int b = blockIdx.x - 64;
    if (t < L_) {
      const float* pp = part + (size_t)b * IMP_G_ * L_ + t;
      float sum = 0.f;
      #pragma unroll 8
      for (int g = 0; g < IMP_G_; ++g) sum += pp[(size_t)g * L_];
      v[t] = sum;
    }
    __syncthreads();
    bool sel = false;
    if (t < L_) {
      const float mv = v[t];
      int cnt = 0;
      #pragma unroll 8
      for (int j = 0; j < L_; ++j) {
        float o = v[j];
        cnt += (o > mv) || (o == mv && j < t);  // stable tie-break
      }
      sel = cnt < K_;
    }
    const unsigned long long ball = __ballot(sel);
    if (lane == 0) wcnt[wave] = __popcll(ball);
    __syncthreads();
    int base = 0;
    for (int w = 0; w < wave; ++w) base += wcnt[w];
    const int pos = base + __popcll(ball & ((1ull << lane) - 1ull));
    if (sel) {
      lidx[pos] = t;
      out1[b * OUTROWS_ + 1 + pos] = mask[b * L_ + t];
    }
    if (t == 0) {
      out1[b * OUTROWS_ + 0] = 0.f;
      out1[b * OUTROWS_ + OUTROWS_ - 1] = 0.f;
    }
    __syncthreads();
    const float4* hb4 = (const float4*)(hidden + (size_t)b * L_ * D_);
    float4* ob4 = (float4*)(out0 + (size_t)b * OUTROWS_ * D_);
    const int NG = (K_ + 1) * 192;  // 129 rows * 192 float4
    for (int i = t; i < NG; i += 768) {
      const int r = i / 192;
      const int c = i - r * 192;
      const int src = (r == 0) ? 0 : lidx[r - 1];
      ob4[r * 192 + c] = hb4[src * 192 + c];
    }
  }
}

// ---------------------------------------------------------------------------
// scores[b,h,l] (masked, scaled) + per-chunk online-softmax stats (max, sumexp).
// Grid (B,16), block 256; wave handles 8 rows; float4 loads.
// ---------------------------------------------------------------------------
__global__ __launch_bounds__(256) void score_kernel(
    const float* __restrict__ hidden, const float* __restrict__ mask,
    const float* __restrict__ wqe, float* __restrict__ scores,
    float* __restrict__ stats) {
  __shared__ float4 wq4[NH_ * 192];
  __shared__ float wstat[4][NH_][2];
  const int b = blockIdx.x, chunk = blockIdx.y, t = threadIdx.x;
  {
    const float4* wsrc = (const float4*)(wqe + (size_t)b * NH_ * D_);
    for (int i = t; i < NH_ * 192; i += 256) wq4[i] = wsrc[i];
  }
  __syncthreads();
  const int wave = t >> 6, lane = t & 63;
  const float scale = 0.03608439182435161f;  // 1/sqrt(768)
  float rm0 = -INFINITY, rm1 = -INFINITY, rm2 = -INFINITY, rm3 = -INFINITY;
  float rs0 = 0.f, rs1 = 0.f, rs2 = 0.f, rs3 = 0.f;
  #pragma unroll
  for (int r = 0; r < 8; ++r) {
    const int l = chunk * 32 + wave * 8 + r;
    const float4* hr4 = (const float4*)(hidden + ((size_t)b * L_ + l) * D_);
    float s0 = 0.f, s1 = 0.f, s2 = 0.f, s3 = 0.f;
    #pragma unroll
    for (int jj = 0; jj < 3; ++jj) {
      const int c = lane + 64 * jj;
      const float4 hv = hr4[c];
      const float4 w0 = wq4[0 * 192 + c];
      const float4 w1 = wq4[1 * 192 + c];
      const float4 w2 = wq4[2 * 192 + c];
      const float4 w3 = wq4[3 * 192 + c];
      s0 += hv.x * w0.x + hv.y * w0.y + hv.z * w0.z + hv.w * w0.w;
      s1 += hv.x * w1.x + hv.y * w1.y + hv.z * w1.z + hv.w * w1.w;
      s2 += hv.x * w2.x + hv.y * w2.y + hv.z * w2.z + hv.w * w2.w;
      s3 += hv.x * w3.x + hv.y * w3.y + hv.z * w3.z + hv.w * w3.w;
    }
    #pragma unroll
    for (int o = 32; o > 0; o >>= 1) {
      s0 += __shfl_down(s0, o, 64);
      s1 += __shfl_down(s1, o, 64);
      s2 += __shfl_down(s2, o, 64);
      s3 += __shfl_down(s3, o, 64);
    }
    if (lane == 0) {
      const bool kp = mask[b * L_ + l] < -10.f;
      const float f0 = kp ? -INFINITY : s0 * scale;
      const float f1 = kp ? -INFINITY : s1 * scale;
      const float f2 = kp ? -INFINITY : s2 * scale;
      const float f3 = kp ? -INFINITY : s3 * scale;
      float* sp = scores + (size_t)b * NH_ * L_ + l;
      sp[0 * L_] = f0; sp[1 * L_] = f1; sp[2 * L_] = f2; sp[3 * L_] = f3;
      if (!kp) {
        float nm;
        nm = fmaxf(rm0, f0); rs0 = rs0 * expf(rm0 - nm) + expf(f0 - nm); rm0 = nm;
        nm = fmaxf(rm1, f1); rs1 = rs1 * expf(rm1 - nm) + expf(f1 - nm); rm1 = nm;
        nm = fmaxf(rm2, f2); rs2 = rs2 * expf(rm2 - nm) + expf(f2 - nm); rm2 = nm;
        nm = fmaxf(rm3, f3); rs3 = rs3 * expf(rm3 - nm) + expf(f3 - nm); rm3 = nm;
      }
    }
  }
  if (lane == 0) {
    wstat[wave][0][0] = rm0; wstat[wave][0][1] = rs0;
    wstat[wave][1][0] = rm1; wstat[wave][1][1] = rs1;
    wstat[wave][2][0] = rm2; wstat[wave][2][1] = rs2;
    wstat[wave][3][0] = rm3; wstat[wave][3][1] = rs3;
  }
  __syncthreads();
  if (t < NH_) {
    float M = -INFINITY, S = 0.f;
    #pragma unroll
    for (int w = 0; w < 4; ++w) M = fmaxf(M, wstat[w][t][0]);
    if (M > -INFINITY) {
      #pragma unroll
      for (int w = 0; w < 4; ++w)
        S += wstat[w][t][1] * expf(wstat[w][t][0] - M);
    }
    float* st = stats + (((size_t)b * NH_ + t) * 16 + chunk) * 2;
    st[0] = M; st[1] = S;
  }
}

// ---------------------------------------------------------------------------
// ctx partials with cheap softmax finalize from chunk stats.
// Grid (B,16), block 768 (t = d, coalesced). No block-wide reductions.
// ---------------------------------------------------------------------------
__global__ __launch_bounds__(768) void ctx_kernel(
    const float* __restrict__ hidden, const float* __restrict__ scores,
    const float* __restrict__ stats, float* __restrict__ ctx_part) {
  __shared__ float pr[NH_][32];
  __shared__ float MS[NH_][2];
  const int b = blockIdx.x, chunk = blockIdx.y, t = threadIdx.x;
  const int l0 = chunk * 32;
  if (t < NH_) {
    const float* st = stats + ((size_t)b * NH_ + t) * 16 * 2;
    float M = -INFINITY;
    #pragma unroll
    for (int c = 0; c < 16; ++c) M = fmaxf(M, st[c * 2]);
    float S = 0.f;
    #pragma unroll
    for (int c = 0; c < 16; ++c) {
      const float m_c = st[c * 2];
      if (m_c > -INFINITY) S += st[c * 2 + 1] * expf(m_c - M);
    }
    MS[t][0] = M; MS[t][1] = S;
  }
  __syncthreads();
  if (t < NH_ * 32) {
    const int h = t >> 5, j = t & 31;
    const float x = scores[((size_t)b * NH_ + h) * L_ + l0 + j];
    pr[h][j] = expf(x - MS[h][0]) / MS[h][1];  // x=-inf -> 0
  }
  __syncthreads();
  const float* hp = hidden + ((size_t)b * L_ + l0) * D_ + t;
  float c0 = 0.f, c1 = 0.f, c2 = 0.f, c3 = 0.f;
  #pragma unroll 8
  for (int l = 0; l < 32; ++l) {
    float hv = hp[(size_t)l * D_];
    c0 += pr[0][l] * hv;
    c1 += pr[1][l] * hv;
    c2 += pr[2][l] * hv;
    c3 += pr[3][l] * hv;
  }
  float* cb = ctx_part + ((size_t)b * 16 + chunk) * NH_ * D_ + t;
  cb[0 * D_] = c0;
  cb[1 * D_] = c1;
  cb[2 * D_] = c2;
  cb[3 * D_] = c3;
}

// ---------------------------------------------------------------------------
// outv[b, h*64+u] = ctx[b,h,:] . Wv[h*64+u, :]. Grid (B,NH), 768 thr.
// ---------------------------------------------------------------------------
__global__ __launch_bounds__(768) void outv_kernel(
    const float* __restrict__ ctx_part, const float* __restrict__ Wv,
    float* __restrict__ outv) {
  __shared__ float ch[D_];
  const int b = blockIdx.x, h = blockIdx.y, t = threadIdx.x;
  const int wave = t >> 6, lane = t & 63;
  {
    float a = 0.f;
    #pragma unroll
    for (int c = 0; c < 16; ++c)
      a += ctx_part[(((size_t)b * 16 + c) * NH_ + h) * D_ + t];
    ch[t] = a;
  }
  __syncthreads();
  for (int u = wave; u < HD_; u += 12) {
    const float* wr = Wv + (size_t)(h * HD_ + u) * D_;
    float acc = 0.f;
    #pragma unroll
    for (int k = 0; k < 12; ++k) {
      const int d = lane + (k << 6);
      acc += wr[d] * ch[d];
    }
    #pragma unroll
    for (int o = 32; o > 0; o >>= 1) acc += __shfl_down(acc, o, 64);
    if (lane == 0) outv[b * U_ + h * HD_ + u] = acc;
  }
}

// ---------------------------------------------------------------------------
// new_token[b,d] = bo[d] + outv[b,:] . Wo[d,:]. Grid (B,4), 192 thr.
// ---------------------------------------------------------------------------
__global__ __launch_bounds__(192) void newtoken_kernel(
    const float* __restrict__ outv, const float* __restrict__ Wo,
    const float* __restrict__ bo, float* __restrict__ out0) {
  __shared__ float4 ov4[64];
  const int b = blockIdx.x, q = blockIdx.y, t = threadIdx.x;
  const int wave = t >> 6, lane = t & 63;
  if (t < 64) ov4[t] = ((const float4*)(outv + b * U_))[t];
  __syncthreads();
  const int dbase = q * 192 + wave * 64;
  const float4 o = ov4[lane];
  for (int i = 0; i < 64; ++i) {
    const int d = dbase + i;
    const float4 w = ((const float4*)(Wo + (size_t)d * U_))[lane];
    float acc = w.x * o.x + w.y * o.y + w.z * o.z + w.w * o.w;
    #pragma unroll
    for (int off = 32; off > 0; off >>= 1) acc += __shfl_down(acc, off, 64);
    if (lane == 0)
      out0[((size_t)b * OUTROWS_ + (OUTROWS_ - 1)) * D_ + d] = bo[d] + acc;
  }
}

extern "C" void kernel_launch(void* const* d_in, const int* in_sizes, int n_in,
                              void* d_out, int out_size, void* d_ws, size_t ws_size,
                              hipStream_t stream) {
  const float* hidden = (const float*)d_in[0];
  const float* mask   = (const float*)d_in[1];
  const float* sas    = (const float*)d_in[2];
  const float* Wq     = (const float*)d_in[3];
  const float* Wk     = (const float*)d_in[4];
  const float* Wv     = (const float*)d_in[5];
  const float* Wo     = (const float*)d_in[6];
  const float* bo     = (const float*)d_in[7];

  float* out0 = (float*)d_out;                       // (B,130,D)
  float* out1 = out0 + (size_t)B_ * OUTROWS_ * D_;   // (B,1,1,130)

  // Workspace (floats) — every buffer fully overwritten before read, no init.
  float* part      = (float*)d_ws;                          // B*96*L
  float* sent_part = part + (size_t)B_ * IMP_G_ * L_;       // B*16*D
  float* ctx_part  = sent_part + (size_t)B_ * 16 * D_;      // B*16*NH*D
  float* wqe       = ctx_part + (size_t)B_ * 16 * NH_ * D_; // B*NH*D
  float* scores    = wqe + (size_t)B_ * NH_ * D_;           // B*NH*L
  float* stats     = scores + (size_t)B_ * NH_ * L_;        // B*NH*16*2
  float* outv      = stats + (size_t)B_ * NH_ * 16 * 2;     // B*U

  imp_sent_kernel<<<dim3(64, B_), 256, 0, stream>>>(sas, hidden, mask,
                                                    part, sent_part);
  qproj_topk_kernel<<<80, 768, 0, stream>>>(sent_part, Wq, Wk, wqe,
                                            part, mask, hidden, out0, out1);
  score_kernel<<<dim3(B_, 16), 256, 0, stream>>>(hidden, mask, wqe,
                                                 scores, stats);
  ctx_kernel<<<dim3(B_, 16), 768, 0, stream>>>(hidden, scores, stats, ctx_part);
  outv_kernel<<<dim3(B_, NH_), 768, 0, stream>>>(ctx_part, Wv, outv);
  newtoken_kernel<<<dim3(B_, 4), 192, 0, stream>>>(outv, Wo, bo, out0);
}